// Round 1
// baseline (405.265 us; speedup 1.0000x reference)
//
#include <hip/hip_runtime.h>
#include <hip/hip_bf16.h>
#include <math.h>

// Problem constants (fixed by setup_inputs): B=32, O=4096, F=256, H=8, HID=128
#define MB_ 131072      // B*O rows
#define F_  256
#define HID_ 128
#define H_  8
#define O_  4096
#define B_  32

static __device__ __forceinline__ unsigned short f2bf(float f) {
    unsigned int u = __float_as_uint(f);
    unsigned int r = (u + 0x7fffu + ((u >> 16) & 1u)) >> 16;  // RNE
    return (unsigned short)r;
}
static __device__ __forceinline__ float bf2f(unsigned short u) {
    return __uint_as_float(((unsigned int)u) << 16);
}
static __device__ __forceinline__ float bflo(unsigned int u) {
    return __uint_as_float(u << 16);
}
static __device__ __forceinline__ float bfhi(unsigned int u) {
    return __uint_as_float(u & 0xffff0000u);
}

// ---------------- Kernel A1: h = relu(x @ W_in + b_in), plus row mask -------
// grid 2048, block 256. 64 rows/block, full 128 cols. K=256 in 4 tiles of 64.
// LDS: a_s padded to 65 (conflict-free scalar reads), b_s 64x128.
__global__ __launch_bounds__(256) void k_gemm_in(
    const float* __restrict__ x, const float* __restrict__ W_in,
    const float* __restrict__ b_in,
    unsigned short* __restrict__ h_out, float* __restrict__ mask_out)
{
    __shared__ float a_s[64 * 65];
    __shared__ float b_s[64 * 128];
    const int tid = threadIdx.x;
    const int R0 = blockIdx.x * 64;
    const int ty = tid >> 5;      // 0..7  -> rows ty*8..ty*8+7
    const int tx = tid & 31;      // 0..31 -> cols tx*4..tx*4+3
    const int kq = tid & 15;      // loader col-quad
    const int r0 = tid >> 4;      // loader row base 0..15

    float acc[8][4];
#pragma unroll
    for (int j = 0; j < 8; j++)
#pragma unroll
        for (int c = 0; c < 4; c++) acc[j][c] = 0.f;
    float msum[4] = {0.f, 0.f, 0.f, 0.f};

    for (int kt = 0; kt < 4; kt++) {
        // stage x tile (64x64), accumulate row sum-of-squares for mask
#pragma unroll
        for (int m = 0; m < 4; m++) {
            const int r = r0 + 16 * m;
            const float4 v = *(const float4*)(x + (size_t)(R0 + r) * F_ + kt * 64 + kq * 4);
            a_s[r * 65 + kq * 4 + 0] = v.x;
            a_s[r * 65 + kq * 4 + 1] = v.y;
            a_s[r * 65 + kq * 4 + 2] = v.z;
            a_s[r * 65 + kq * 4 + 3] = v.w;
            msum[m] += v.x * v.x + v.y * v.y + v.z * v.z + v.w * v.w;
        }
        // stage W_in tile (64x128)
        {
            const int cq = tid & 31;
            const int kr = tid >> 5;
#pragma unroll
            for (int m = 0; m < 8; m++) {
                const float4 v = *(const float4*)(W_in + (size_t)(kt * 64 + kr + 8 * m) * HID_ + cq * 4);
                *(float4*)(&b_s[(kr + 8 * m) * 128 + cq * 4]) = v;
            }
        }
        __syncthreads();
#pragma unroll 4
        for (int k = 0; k < 64; k++) {
            float av[8];
#pragma unroll
            for (int j = 0; j < 8; j++) av[j] = a_s[(ty * 8 + j) * 65 + k];
            const float4 bv = *(const float4*)(&b_s[k * 128 + tx * 4]);
#pragma unroll
            for (int j = 0; j < 8; j++) {
                acc[j][0] += av[j] * bv.x;
                acc[j][1] += av[j] * bv.y;
                acc[j][2] += av[j] * bv.z;
                acc[j][3] += av[j] * bv.w;
            }
        }
        __syncthreads();
    }
    float bias[4];
#pragma unroll
    for (int c = 0; c < 4; c++) bias[c] = b_in[tx * 4 + c];
#pragma unroll
    for (int j = 0; j < 8; j++) {
        const size_t r = (size_t)R0 + ty * 8 + j;
        ushort4 o;
        o.x = f2bf(fmaxf(acc[j][0] + bias[0], 0.f));
        o.y = f2bf(fmaxf(acc[j][1] + bias[1], 0.f));
        o.z = f2bf(fmaxf(acc[j][2] + bias[2], 0.f));
        o.w = f2bf(fmaxf(acc[j][3] + bias[3], 0.f));
        *(ushort4*)(h_out + r * HID_ + tx * 4) = o;
    }
    // mask: reduce msum over the 16 kq lanes (consecutive within a wave)
#pragma unroll
    for (int m = 0; m < 4; m++) {
        float s = msum[m];
        s += __shfl_down(s, 8, 16);
        s += __shfl_down(s, 4, 16);
        s += __shfl_down(s, 2, 16);
        s += __shfl_down(s, 1, 16);
        if (kq == 0) mask_out[R0 + r0 + 16 * m] = (s != 0.f) ? 1.f : 0.f;
    }
}

// ---------------- Kernel A2: z = h @ W_blk + b_blk, + BN column partials ----
// grid 2048, block 256. K=128 in 2 tiles of 64.
__global__ __launch_bounds__(256) void k_gemm_blk(
    const unsigned short* __restrict__ h_in, const float* __restrict__ W_blk,
    const float* __restrict__ b_blk, unsigned short* __restrict__ z_out,
    float* __restrict__ sumP, float* __restrict__ sumsqP)
{
    __shared__ float a_s[64 * 65];
    __shared__ float b_s[64 * 128];
    __shared__ float csum[128];
    __shared__ float csumsq[128];
    const int tid = threadIdx.x;
    const int R0 = blockIdx.x * 64;
    const int ty = tid >> 5;
    const int tx = tid & 31;
    const int kq = tid & 15;
    const int r0 = tid >> 4;
    if (tid < 128) { csum[tid] = 0.f; csumsq[tid] = 0.f; }

    float acc[8][4];
#pragma unroll
    for (int j = 0; j < 8; j++)
#pragma unroll
        for (int c = 0; c < 4; c++) acc[j][c] = 0.f;

    for (int kt = 0; kt < 2; kt++) {
#pragma unroll
        for (int m = 0; m < 4; m++) {
            const int r = r0 + 16 * m;
            const ushort4 v = *(const ushort4*)(h_in + (size_t)(R0 + r) * HID_ + kt * 64 + kq * 4);
            a_s[r * 65 + kq * 4 + 0] = bf2f(v.x);
            a_s[r * 65 + kq * 4 + 1] = bf2f(v.y);
            a_s[r * 65 + kq * 4 + 2] = bf2f(v.z);
            a_s[r * 65 + kq * 4 + 3] = bf2f(v.w);
        }
        {
            const int cq = tid & 31;
            const int kr = tid >> 5;
#pragma unroll
            for (int m = 0; m < 8; m++) {
                const float4 v = *(const float4*)(W_blk + (size_t)(kt * 64 + kr + 8 * m) * HID_ + cq * 4);
                *(float4*)(&b_s[(kr + 8 * m) * 128 + cq * 4]) = v;
            }
        }
        __syncthreads();
#pragma unroll 4
        for (int k = 0; k < 64; k++) {
            float av[8];
#pragma unroll
            for (int j = 0; j < 8; j++) av[j] = a_s[(ty * 8 + j) * 65 + k];
            const float4 bv = *(const float4*)(&b_s[k * 128 + tx * 4]);
#pragma unroll
            for (int j = 0; j < 8; j++) {
                acc[j][0] += av[j] * bv.x;
                acc[j][1] += av[j] * bv.y;
                acc[j][2] += av[j] * bv.z;
                acc[j][3] += av[j] * bv.w;
            }
        }
        __syncthreads();
    }
    float bias[4];
#pragma unroll
    for (int c = 0; c < 4; c++) bias[c] = b_blk[tx * 4 + c];
    float ls[4] = {0.f, 0.f, 0.f, 0.f}, lss[4] = {0.f, 0.f, 0.f, 0.f};
#pragma unroll
    for (int j = 0; j < 8; j++) {
        const size_t r = (size_t)R0 + ty * 8 + j;
        float zv[4];
#pragma unroll
        for (int c = 0; c < 4; c++) {
            zv[c] = acc[j][c] + bias[c];
            ls[c] += zv[c];
            lss[c] += zv[c] * zv[c];
        }
        ushort4 o;
        o.x = f2bf(zv[0]); o.y = f2bf(zv[1]); o.z = f2bf(zv[2]); o.w = f2bf(zv[3]);
        *(ushort4*)(z_out + r * HID_ + tx * 4) = o;
    }
#pragma unroll
    for (int c = 0; c < 4; c++) {
        atomicAdd(&csum[tx * 4 + c], ls[c]);
        atomicAdd(&csumsq[tx * 4 + c], lss[c]);
    }
    __syncthreads();
    if (tid < 128) {
        sumP[(size_t)blockIdx.x * 128 + tid] = csum[tid];
        sumsqP[(size_t)blockIdx.x * 128 + tid] = csumsq[tid];
    }
}

// ---------------- Kernel B: finalize BN -> scale/shift ----------------------
// grid 128 (one block per column), block 256
__global__ __launch_bounds__(256) void k_bnfin(
    const float* __restrict__ sumP, const float* __restrict__ sumsqP,
    const float* __restrict__ gamma, const float* __restrict__ beta,
    float* __restrict__ scale, float* __restrict__ shift)
{
    const int c = blockIdx.x;
    const int tid = threadIdx.x;
    float s = 0.f, ss = 0.f;
    for (int i = tid; i < 2048; i += 256) {
        s  += sumP[(size_t)i * 128 + c];
        ss += sumsqP[(size_t)i * 128 + c];
    }
#pragma unroll
    for (int off = 32; off; off >>= 1) {
        s  += __shfl_xor(s, off, 64);
        ss += __shfl_xor(ss, off, 64);
    }
    __shared__ float rs[4], rss[4];
    const int wid = tid >> 6, lane = tid & 63;
    if (lane == 0) { rs[wid] = s; rss[wid] = ss; }
    __syncthreads();
    if (tid == 0) {
        const float S  = rs[0] + rs[1] + rs[2] + rs[3];
        const float SS = rss[0] + rss[1] + rss[2] + rss[3];
        const float inv_m = 1.0f / (float)MB_;
        const float mu = S * inv_m;
        const float var = SS * inv_m - mu * mu;
        const float sc = gamma[c] * rsqrtf(var + 1e-5f);
        scale[c] = sc;
        shift[c] = beta[c] - mu * sc;
    }
}

// ---------------- Kernel C: BN apply + residual + logits + gumbel -----------
// t = ((relu(z*scale+shift)+h) @ W_fc + b_fc) * mask + gumbel   (TAU=1)
// grid 512, block 256; one row per thread.
__global__ __launch_bounds__(256) void k_logits(
    const unsigned short* __restrict__ h_in, const unsigned short* __restrict__ z_in,
    const float* __restrict__ scale, const float* __restrict__ shift,
    const float* __restrict__ W_fc, const float* __restrict__ b_fc,
    const float* __restrict__ mask, const float* __restrict__ gumbel,
    float* __restrict__ t_out)
{
    __shared__ float wfc_s[128 * 8];
    __shared__ float sc_s[128], sh_s[128];
    const int tid = threadIdx.x;
    for (int i = tid; i < 1024; i += 256) wfc_s[i] = W_fc[i];
    if (tid < 128) { sc_s[tid] = scale[tid]; sh_s[tid] = shift[tid]; }
    __syncthreads();

    const size_t row = (size_t)blockIdx.x * 256 + tid;
    float acc[8];
#pragma unroll
    for (int j = 0; j < 8; j++) acc[j] = 0.f;

    const uint4* hp = (const uint4*)(h_in + row * HID_);
    const uint4* zp = (const uint4*)(z_in + row * HID_);
#pragma unroll 2
    for (int kc = 0; kc < 16; kc++) {
        const uint4 hq = hp[kc];
        const uint4 zq = zp[kc];
        unsigned int hs[4] = {hq.x, hq.y, hq.z, hq.w};
        unsigned int zs[4] = {zq.x, zq.y, zq.z, zq.w};
#pragma unroll
        for (int p = 0; p < 4; p++) {
            const int k = kc * 8 + p * 2;
            const float hf0 = bflo(hs[p]), hf1 = bfhi(hs[p]);
            const float zf0 = bflo(zs[p]), zf1 = bfhi(zs[p]);
            const float hb0 = fmaxf(zf0 * sc_s[k] + sh_s[k], 0.f) + hf0;
            const float hb1 = fmaxf(zf1 * sc_s[k + 1] + sh_s[k + 1], 0.f) + hf1;
#pragma unroll
            for (int j = 0; j < 8; j++)
                acc[j] += hb0 * wfc_s[k * 8 + j] + hb1 * wfc_s[(k + 1) * 8 + j];
        }
    }
    const float mk = mask[row];
    const float4 g0 = *(const float4*)(gumbel + row * 8);
    const float4 g1 = *(const float4*)(gumbel + row * 8 + 4);
    float4 t0, t1;
    t0.x = (acc[0] + b_fc[0]) * mk + g0.x;
    t0.y = (acc[1] + b_fc[1]) * mk + g0.y;
    t0.z = (acc[2] + b_fc[2]) * mk + g0.z;
    t0.w = (acc[3] + b_fc[3]) * mk + g0.w;
    t1.x = (acc[4] + b_fc[4]) * mk + g1.x;
    t1.y = (acc[5] + b_fc[5]) * mk + g1.y;
    t1.z = (acc[6] + b_fc[6]) * mk + g1.z;
    t1.w = (acc[7] + b_fc[7]) * mk + g1.w;
    *(float4*)(t_out + row * 8) = t0;
    *(float4*)(t_out + row * 8 + 4) = t1;
}

// ---------------- Kernel D: softmax over O per (b,h) ------------------------
// grid 256 (= b*8+h), block 256; writes w in (b,h,o) layout
__global__ __launch_bounds__(256) void k_softmax(
    const float* __restrict__ t_in, float* __restrict__ w_out)
{
    const int bh = blockIdx.x;
    const int b = bh >> 3, hh = bh & 7;
    const int tid = threadIdx.x;
    const float* tp = t_in + (size_t)b * O_ * H_ + hh;
    float v[16];
    float mx = -3.4e38f;
#pragma unroll
    for (int it = 0; it < 16; it++) {
        v[it] = tp[(size_t)(it * 256 + tid) * 8];
        mx = fmaxf(mx, v[it]);
    }
#pragma unroll
    for (int off = 32; off; off >>= 1) mx = fmaxf(mx, __shfl_xor(mx, off, 64));
    __shared__ float rm[4];
    __shared__ float rsum[4];
    const int wid = tid >> 6, lane = tid & 63;
    if (lane == 0) rm[wid] = mx;
    __syncthreads();
    mx = fmaxf(fmaxf(rm[0], rm[1]), fmaxf(rm[2], rm[3]));
    float sum = 0.f;
#pragma unroll
    for (int it = 0; it < 16; it++) { v[it] = __expf(v[it] - mx); sum += v[it]; }
#pragma unroll
    for (int off = 32; off; off >>= 1) sum += __shfl_xor(sum, off, 64);
    if (lane == 0) rsum[wid] = sum;
    __syncthreads();
    sum = rsum[0] + rsum[1] + rsum[2] + rsum[3];
    const float inv = 1.f / sum;
    float* wp = w_out + (size_t)bh * O_;
#pragma unroll
    for (int it = 0; it < 16; it++) wp[it * 256 + tid] = v[it] * inv;
}

// ---------------- Kernel E: pooled partials ---------------------------------
// pooled[b,h,f] = sum_o w[b,h,o]*x[b,o,f]; grid (oc=16, b=32), block 256 (f)
__global__ __launch_bounds__(256) void k_pool(
    const float* __restrict__ x, const float* __restrict__ w_in,
    float* __restrict__ pp)
{
    __shared__ float ws_s[8][256];
    const int tid = threadIdx.x;
    const int oc = blockIdx.x;
    const int b = blockIdx.y;
#pragma unroll
    for (int hh = 0; hh < 8; hh++)
        ws_s[hh][tid] = w_in[((size_t)(b * 8 + hh)) * O_ + oc * 256 + tid];
    __syncthreads();
    float acc[8];
#pragma unroll
    for (int hh = 0; hh < 8; hh++) acc[hh] = 0.f;
    const float* xp = x + ((size_t)b * O_ + oc * 256) * F_ + tid;
    for (int o = 0; o < 256; o++) {
        const float xv = xp[(size_t)o * F_];
#pragma unroll
        for (int hh = 0; hh < 8; hh++) acc[hh] += ws_s[hh][o] * xv;
    }
    float* outp = pp + ((size_t)oc * 32 + b) * 2048;
#pragma unroll
    for (int hh = 0; hh < 8; hh++) outp[hh * 256 + tid] = acc[hh];
}

// ---------------- Kernel F: reduce pooled partials --------------------------
// grid 256, block 256 -> 65536 outputs
__global__ __launch_bounds__(256) void k_reduce_pool(
    const float* __restrict__ pp, float* __restrict__ out)
{
    const size_t i = (size_t)blockIdx.x * 256 + threadIdx.x;
    float s = 0.f;
#pragma unroll
    for (int oc = 0; oc < 16; oc++) s += pp[(size_t)oc * 65536 + i];
    out[i] = s;
}

extern "C" void kernel_launch(void* const* d_in, const int* in_sizes, int n_in,
                              void* d_out, int out_size, void* d_ws, size_t ws_size,
                              hipStream_t stream)
{
    const float* x      = (const float*)d_in[0];
    const float* gumbel = (const float*)d_in[1];
    const float* W_in   = (const float*)d_in[2];
    const float* b_in   = (const float*)d_in[3];
    const float* W_blk  = (const float*)d_in[4];
    const float* b_blk  = (const float*)d_in[5];
    const float* gamma  = (const float*)d_in[6];
    const float* beta   = (const float*)d_in[7];
    const float* W_fc   = (const float*)d_in[8];
    const float* b_fc   = (const float*)d_in[9];
    float* out = (float*)d_out;
    char* ws = (char*)d_ws;

    // workspace layout (bytes) — total ~82.3 MB
    unsigned short* h_bf  = (unsigned short*)(ws + 0);            // 33554432
    unsigned short* z_bf  = (unsigned short*)(ws + 33554432);     // 33554432
    float* mask   = (float*)(ws + 67108864);                       // 524288
    float* sumP   = (float*)(ws + 67633152);                       // 1048576
    float* sumsqP = (float*)(ws + 68681728);                       // 1048576
    float* scale  = (float*)(ws + 69730304);                       // 512
    float* shift  = (float*)(ws + 69730816);                       // 512
    float* t_buf  = (float*)(ws + 69731328);                       // 4194304
    float* w_buf  = (float*)(ws + 73925632);                       // 4194304
    float* pp     = (float*)(ws + 78119936);                       // 4194304

    k_gemm_in<<<2048, 256, 0, stream>>>(x, W_in, b_in, h_bf, mask);
    k_gemm_blk<<<2048, 256, 0, stream>>>(h_bf, W_blk, b_blk, z_bf, sumP, sumsqP);
    k_bnfin<<<128, 256, 0, stream>>>(sumP, sumsqP, gamma, beta, scale, shift);
    k_logits<<<512, 256, 0, stream>>>(h_bf, z_bf, scale, shift, W_fc, b_fc, mask, gumbel, t_buf);
    k_softmax<<<256, 256, 0, stream>>>(t_buf, w_buf);
    k_pool<<<dim3(16, 32), 256, 0, stream>>>(x, w_buf, pp);
    k_reduce_pool<<<256, 256, 0, stream>>>(pp, out);
}

// Round 2
// 303.485 us; speedup vs baseline: 1.3354x; 1.3354x over previous
//
#include <hip/hip_runtime.h>
#include <hip/hip_bf16.h>
#include <math.h>

// Problem constants: B=32, O=4096, F=256, H=8, HID=128
#define MB_ 131072
#define F_  256
#define HID_ 128
#define H_  8
#define O_  4096
#define B_  32

typedef __attribute__((ext_vector_type(8))) short short8;
typedef __attribute__((ext_vector_type(4))) float f32x4;

static __device__ __forceinline__ unsigned short f2bf(float f) {
    unsigned int u = __float_as_uint(f);
    unsigned int r = (u + 0x7fffu + ((u >> 16) & 1u)) >> 16;  // RNE
    return (unsigned short)r;
}
static __device__ __forceinline__ float bf2f(unsigned short u) {
    return __uint_as_float(((unsigned int)u) << 16);
}
static __device__ __forceinline__ float bflo(unsigned int u) {
    return __uint_as_float(u << 16);
}
static __device__ __forceinline__ float bfhi(unsigned int u) {
    return __uint_as_float(u & 0xffff0000u);
}

// ---------------- Prep: transpose + bf16-cast weights -----------------------
// WinT[n][k] (128x256) from W_in[k][n] (256x128); WblkT[n][k] (128x128)
__global__ __launch_bounds__(256) void k_prep(
    const float* __restrict__ W_in, const float* __restrict__ W_blk,
    unsigned short* __restrict__ WinT, unsigned short* __restrict__ WblkT)
{
    const int idx = blockIdx.x * 256 + threadIdx.x;
    if (idx < 32768) {
        const int n = idx >> 8, k = idx & 255;
        WinT[idx] = f2bf(W_in[(size_t)k * HID_ + n]);
    } else {
        const int i2 = idx - 32768;  // < 16384
        const int n = i2 >> 7, k = i2 & 127;
        WblkT[i2] = f2bf(W_blk[(size_t)k * HID_ + n]);
    }
}

// ---------------- MFMA GEMM1: h = relu(x @ W_in + b_in) + row mask ----------
// grid 1024, block 256 (4 waves). Tile 128x128, K=256 in 8 tiles of 32.
__global__ __launch_bounds__(256) void k_mfma_in(
    const float* __restrict__ x, const unsigned short* __restrict__ WinT,
    const float* __restrict__ b_in,
    unsigned short* __restrict__ h_out, float* __restrict__ mask_out)
{
    __shared__ unsigned short a_s[128 * 40];  // +8 pad, 16B-aligned rows
    __shared__ unsigned short b_s[128 * 40];
    __shared__ float msum_s[128];
    const int tid = threadIdx.x;
    const int R0 = blockIdx.x * 128;
    const int lp_r = tid >> 3;   // 0..31
    const int lp_c = tid & 7;    // 0..7 (float4 chunk)
    const int wave = tid >> 6;
    const int wrow = wave >> 1, wcol = wave & 1;
    const int lane = tid & 63;
    const int lm = lane & 15, quad = lane >> 4;

    if (tid < 128) msum_s[tid] = 0.f;
    float ms[4] = {0.f, 0.f, 0.f, 0.f};

    f32x4 acc[4][4];
#pragma unroll
    for (int i = 0; i < 4; i++)
#pragma unroll
        for (int j = 0; j < 4; j++) acc[i][j] = (f32x4){0.f, 0.f, 0.f, 0.f};

    for (int kt = 0; kt < 8; kt++) {
#pragma unroll
        for (int p = 0; p < 4; p++) {
            const int r = lp_r + 32 * p;
            const float4 v = *(const float4*)(x + (size_t)(R0 + r) * F_ + kt * 32 + lp_c * 4);
            ms[p] += v.x * v.x + v.y * v.y + v.z * v.z + v.w * v.w;
            ushort4 o;
            o.x = f2bf(v.x); o.y = f2bf(v.y); o.z = f2bf(v.z); o.w = f2bf(v.w);
            *(ushort4*)(&a_s[r * 40 + lp_c * 4]) = o;
        }
#pragma unroll
        for (int p = 0; p < 4; p++) {
            const int n = lp_r + 32 * p;
            const ushort4 wv = *(const ushort4*)(WinT + (size_t)n * F_ + kt * 32 + lp_c * 4);
            *(ushort4*)(&b_s[n * 40 + lp_c * 4]) = wv;
        }
        __syncthreads();
        short8 af[4], bfr[4];
#pragma unroll
        for (int mi = 0; mi < 4; mi++)
            af[mi] = *(const short8*)(&a_s[(wrow * 64 + mi * 16 + lm) * 40 + quad * 8]);
#pragma unroll
        for (int ni = 0; ni < 4; ni++)
            bfr[ni] = *(const short8*)(&b_s[(wcol * 64 + ni * 16 + lm) * 40 + quad * 8]);
#pragma unroll
        for (int mi = 0; mi < 4; mi++)
#pragma unroll
            for (int ni = 0; ni < 4; ni++)
                acc[mi][ni] = __builtin_amdgcn_mfma_f32_16x16x32_bf16(af[mi], bfr[ni], acc[mi][ni], 0, 0, 0);
        __syncthreads();
    }

    // row mask
#pragma unroll
    for (int p = 0; p < 4; p++) atomicAdd(&msum_s[lp_r + 32 * p], ms[p]);

    // epilogue: bias + relu + bf16 store
    float bcol[4];
#pragma unroll
    for (int ni = 0; ni < 4; ni++) bcol[ni] = b_in[wcol * 64 + ni * 16 + lm];
#pragma unroll
    for (int mi = 0; mi < 4; mi++)
#pragma unroll
        for (int r = 0; r < 4; r++) {
            const size_t row = (size_t)R0 + wrow * 64 + mi * 16 + quad * 4 + r;
#pragma unroll
            for (int ni = 0; ni < 4; ni++) {
                const float v = fmaxf(acc[mi][ni][r] + bcol[ni], 0.f);
                h_out[row * HID_ + wcol * 64 + ni * 16 + lm] = f2bf(v);
            }
        }
    __syncthreads();
    if (tid < 128) mask_out[R0 + tid] = (msum_s[tid] != 0.f) ? 1.f : 0.f;
}

// ---------------- MFMA GEMM2: z = h @ W_blk + b_blk, + BN partials ----------
// grid 1024, block 256. K=128 in 4 tiles of 32.
__global__ __launch_bounds__(256) void k_mfma_blk(
    const unsigned short* __restrict__ h_in, const unsigned short* __restrict__ WblkT,
    const float* __restrict__ b_blk, unsigned short* __restrict__ z_out,
    float* __restrict__ sumP, float* __restrict__ sumsqP)
{
    __shared__ unsigned short a_s[128 * 40];
    __shared__ unsigned short b_s[128 * 40];
    __shared__ float csum_s[128], csumsq_s[128];
    const int tid = threadIdx.x;
    const int R0 = blockIdx.x * 128;
    const int lp_r = tid >> 3;
    const int lp_c = tid & 7;
    const int wave = tid >> 6;
    const int wrow = wave >> 1, wcol = wave & 1;
    const int lane = tid & 63;
    const int lm = lane & 15, quad = lane >> 4;

    if (tid < 128) { csum_s[tid] = 0.f; csumsq_s[tid] = 0.f; }

    f32x4 acc[4][4];
#pragma unroll
    for (int i = 0; i < 4; i++)
#pragma unroll
        for (int j = 0; j < 4; j++) acc[i][j] = (f32x4){0.f, 0.f, 0.f, 0.f};

    for (int kt = 0; kt < 4; kt++) {
#pragma unroll
        for (int p = 0; p < 4; p++) {
            const int r = lp_r + 32 * p;
            const ushort4 v = *(const ushort4*)(h_in + (size_t)(R0 + r) * HID_ + kt * 32 + lp_c * 4);
            *(ushort4*)(&a_s[r * 40 + lp_c * 4]) = v;
        }
#pragma unroll
        for (int p = 0; p < 4; p++) {
            const int n = lp_r + 32 * p;
            const ushort4 wv = *(const ushort4*)(WblkT + (size_t)n * HID_ + kt * 32 + lp_c * 4);
            *(ushort4*)(&b_s[n * 40 + lp_c * 4]) = wv;
        }
        __syncthreads();
        short8 af[4], bfr[4];
#pragma unroll
        for (int mi = 0; mi < 4; mi++)
            af[mi] = *(const short8*)(&a_s[(wrow * 64 + mi * 16 + lm) * 40 + quad * 8]);
#pragma unroll
        for (int ni = 0; ni < 4; ni++)
            bfr[ni] = *(const short8*)(&b_s[(wcol * 64 + ni * 16 + lm) * 40 + quad * 8]);
#pragma unroll
        for (int mi = 0; mi < 4; mi++)
#pragma unroll
            for (int ni = 0; ni < 4; ni++)
                acc[mi][ni] = __builtin_amdgcn_mfma_f32_16x16x32_bf16(af[mi], bfr[ni], acc[mi][ni], 0, 0, 0);
        __syncthreads();
    }

    float bcol[4];
#pragma unroll
    for (int ni = 0; ni < 4; ni++) bcol[ni] = b_blk[wcol * 64 + ni * 16 + lm];
    float s_c[4] = {0.f, 0.f, 0.f, 0.f}, ss_c[4] = {0.f, 0.f, 0.f, 0.f};
#pragma unroll
    for (int mi = 0; mi < 4; mi++)
#pragma unroll
        for (int r = 0; r < 4; r++) {
            const size_t row = (size_t)R0 + wrow * 64 + mi * 16 + quad * 4 + r;
#pragma unroll
            for (int ni = 0; ni < 4; ni++) {
                const float zv = acc[mi][ni][r] + bcol[ni];
                s_c[ni] += zv;
                ss_c[ni] += zv * zv;
                z_out[row * HID_ + wcol * 64 + ni * 16 + lm] = f2bf(zv);
            }
        }
#pragma unroll
    for (int ni = 0; ni < 4; ni++) {
        atomicAdd(&csum_s[wcol * 64 + ni * 16 + lm], s_c[ni]);
        atomicAdd(&csumsq_s[wcol * 64 + ni * 16 + lm], ss_c[ni]);
    }
    __syncthreads();
    if (tid < 128) {
        sumP[(size_t)blockIdx.x * 128 + tid] = csum_s[tid];
        sumsqP[(size_t)blockIdx.x * 128 + tid] = csumsq_s[tid];
    }
}

// ---------------- BN finalize ----------------------------------------------
__global__ __launch_bounds__(256) void k_bnfin(
    const float* __restrict__ sumP, const float* __restrict__ sumsqP,
    const float* __restrict__ gamma, const float* __restrict__ beta,
    float* __restrict__ scale, float* __restrict__ shift)
{
    const int c = blockIdx.x;
    const int tid = threadIdx.x;
    float s = 0.f, ss = 0.f;
    for (int i = tid; i < 1024; i += 256) {
        s  += sumP[(size_t)i * 128 + c];
        ss += sumsqP[(size_t)i * 128 + c];
    }
#pragma unroll
    for (int off = 32; off; off >>= 1) {
        s  += __shfl_xor(s, off, 64);
        ss += __shfl_xor(ss, off, 64);
    }
    __shared__ float rs[4], rss[4];
    const int wid = tid >> 6, lane = tid & 63;
    if (lane == 0) { rs[wid] = s; rss[wid] = ss; }
    __syncthreads();
    if (tid == 0) {
        const float S  = rs[0] + rs[1] + rs[2] + rs[3];
        const float SS = rss[0] + rss[1] + rss[2] + rss[3];
        const float inv_m = 1.0f / (float)MB_;
        const float mu = S * inv_m;
        const float var = SS * inv_m - mu * mu;
        const float sc = gamma[c] * rsqrtf(var + 1e-5f);
        scale[c] = sc;
        shift[c] = beta[c] - mu * sc;
    }
}

// ---------------- logits + gumbel ------------------------------------------
__global__ __launch_bounds__(256) void k_logits(
    const unsigned short* __restrict__ h_in, const unsigned short* __restrict__ z_in,
    const float* __restrict__ scale, const float* __restrict__ shift,
    const float* __restrict__ W_fc, const float* __restrict__ b_fc,
    const float* __restrict__ mask, const float* __restrict__ gumbel,
    float* __restrict__ t_out)
{
    __shared__ float wfc_s[128 * 8];
    __shared__ float sc_s[128], sh_s[128];
    const int tid = threadIdx.x;
    for (int i = tid; i < 1024; i += 256) wfc_s[i] = W_fc[i];
    if (tid < 128) { sc_s[tid] = scale[tid]; sh_s[tid] = shift[tid]; }
    __syncthreads();

    const size_t row = (size_t)blockIdx.x * 256 + tid;
    float acc[8];
#pragma unroll
    for (int j = 0; j < 8; j++) acc[j] = 0.f;

    const uint4* hp = (const uint4*)(h_in + row * HID_);
    const uint4* zp = (const uint4*)(z_in + row * HID_);
#pragma unroll 2
    for (int kc = 0; kc < 16; kc++) {
        const uint4 hq = hp[kc];
        const uint4 zq = zp[kc];
        unsigned int hs[4] = {hq.x, hq.y, hq.z, hq.w};
        unsigned int zs[4] = {zq.x, zq.y, zq.z, zq.w};
#pragma unroll
        for (int p = 0; p < 4; p++) {
            const int k = kc * 8 + p * 2;
            const float hf0 = bflo(hs[p]), hf1 = bfhi(hs[p]);
            const float zf0 = bflo(zs[p]), zf1 = bfhi(zs[p]);
            const float hb0 = fmaxf(zf0 * sc_s[k] + sh_s[k], 0.f) + hf0;
            const float hb1 = fmaxf(zf1 * sc_s[k + 1] + sh_s[k + 1], 0.f) + hf1;
#pragma unroll
            for (int j = 0; j < 8; j++)
                acc[j] += hb0 * wfc_s[k * 8 + j] + hb1 * wfc_s[(k + 1) * 8 + j];
        }
    }
    const float mk = mask[row];
    const float4 g0 = *(const float4*)(gumbel + row * 8);
    const float4 g1 = *(const float4*)(gumbel + row * 8 + 4);
    float4 t0, t1;
    t0.x = (acc[0] + b_fc[0]) * mk + g0.x;
    t0.y = (acc[1] + b_fc[1]) * mk + g0.y;
    t0.z = (acc[2] + b_fc[2]) * mk + g0.z;
    t0.w = (acc[3] + b_fc[3]) * mk + g0.w;
    t1.x = (acc[4] + b_fc[4]) * mk + g1.x;
    t1.y = (acc[5] + b_fc[5]) * mk + g1.y;
    t1.z = (acc[6] + b_fc[6]) * mk + g1.z;
    t1.w = (acc[7] + b_fc[7]) * mk + g1.w;
    *(float4*)(t_out + row * 8) = t0;
    *(float4*)(t_out + row * 8 + 4) = t1;
}

// ---------------- softmax over O per (b,h) ----------------------------------
__global__ __launch_bounds__(256) void k_softmax(
    const float* __restrict__ t_in, float* __restrict__ w_out)
{
    const int bh = blockIdx.x;
    const int b = bh >> 3, hh = bh & 7;
    const int tid = threadIdx.x;
    const float* tp = t_in + (size_t)b * O_ * H_ + hh;
    float v[16];
    float mx = -3.4e38f;
#pragma unroll
    for (int it = 0; it < 16; it++) {
        v[it] = tp[(size_t)(it * 256 + tid) * 8];
        mx = fmaxf(mx, v[it]);
    }
#pragma unroll
    for (int off = 32; off; off >>= 1) mx = fmaxf(mx, __shfl_xor(mx, off, 64));
    __shared__ float rm[4];
    __shared__ float rsum[4];
    const int wid = tid >> 6, lane = tid & 63;
    if (lane == 0) rm[wid] = mx;
    __syncthreads();
    mx = fmaxf(fmaxf(rm[0], rm[1]), fmaxf(rm[2], rm[3]));
    float sum = 0.f;
#pragma unroll
    for (int it = 0; it < 16; it++) { v[it] = __expf(v[it] - mx); sum += v[it]; }
#pragma unroll
    for (int off = 32; off; off >>= 1) sum += __shfl_xor(sum, off, 64);
    if (lane == 0) rsum[wid] = sum;
    __syncthreads();
    sum = rsum[0] + rsum[1] + rsum[2] + rsum[3];
    const float inv = 1.f / sum;
    float* wp = w_out + (size_t)bh * O_;
#pragma unroll
    for (int it = 0; it < 16; it++) wp[it * 256 + tid] = v[it] * inv;
}

// ---------------- pooled partials -------------------------------------------
__global__ __launch_bounds__(256) void k_pool(
    const float* __restrict__ x, const float* __restrict__ w_in,
    float* __restrict__ pp)
{
    __shared__ float ws_s[8][256];
    const int tid = threadIdx.x;
    const int oc = blockIdx.x;
    const int b = blockIdx.y;
#pragma unroll
    for (int hh = 0; hh < 8; hh++)
        ws_s[hh][tid] = w_in[((size_t)(b * 8 + hh)) * O_ + oc * 256 + tid];
    __syncthreads();
    float acc[8];
#pragma unroll
    for (int hh = 0; hh < 8; hh++) acc[hh] = 0.f;
    const float* xp = x + ((size_t)b * O_ + oc * 256) * F_ + tid;
    for (int o = 0; o < 256; o++) {
        const float xv = xp[(size_t)o * F_];
#pragma unroll
        for (int hh = 0; hh < 8; hh++) acc[hh] += ws_s[hh][o] * xv;
    }
    float* outp = pp + ((size_t)oc * 32 + b) * 2048;
#pragma unroll
    for (int hh = 0; hh < 8; hh++) outp[hh * 256 + tid] = acc[hh];
}

// ---------------- reduce pooled partials ------------------------------------
__global__ __launch_bounds__(256) void k_reduce_pool(
    const float* __restrict__ pp, float* __restrict__ out)
{
    const size_t i = (size_t)blockIdx.x * 256 + threadIdx.x;
    float s = 0.f;
#pragma unroll
    for (int oc = 0; oc < 16; oc++) s += pp[(size_t)oc * 65536 + i];
    out[i] = s;
}

extern "C" void kernel_launch(void* const* d_in, const int* in_sizes, int n_in,
                              void* d_out, int out_size, void* d_ws, size_t ws_size,
                              hipStream_t stream)
{
    const float* x      = (const float*)d_in[0];
    const float* gumbel = (const float*)d_in[1];
    const float* W_in   = (const float*)d_in[2];
    const float* b_in   = (const float*)d_in[3];
    const float* W_blk  = (const float*)d_in[4];
    const float* b_blk  = (const float*)d_in[5];
    const float* gamma  = (const float*)d_in[6];
    const float* beta   = (const float*)d_in[7];
    const float* W_fc   = (const float*)d_in[8];
    const float* b_fc   = (const float*)d_in[9];
    float* out = (float*)d_out;
    char* ws = (char*)d_ws;

    unsigned short* h_bf  = (unsigned short*)(ws + 0);            // 33554432
    unsigned short* z_bf  = (unsigned short*)(ws + 33554432);     // 33554432
    float* mask   = (float*)(ws + 67108864);                       // 524288
    float* sumP   = (float*)(ws + 67633152);                       // 524288
    float* sumsqP = (float*)(ws + 68157440);                       // 524288
    float* scale  = (float*)(ws + 68681728);                       // 512
    float* shift  = (float*)(ws + 68682240);                       // 512
    float* t_buf  = (float*)(ws + 68682752);                       // 4194304
    float* w_buf  = (float*)(ws + 72877056);                       // 4194304
    float* pp     = (float*)(ws + 77071360);                       // 4194304
    unsigned short* WinT  = (unsigned short*)(ws + 81265664);      // 65536
    unsigned short* WblkT = (unsigned short*)(ws + 81331200);      // 32768

    k_prep<<<192, 256, 0, stream>>>(W_in, W_blk, WinT, WblkT);
    k_mfma_in<<<1024, 256, 0, stream>>>(x, WinT, b_in, h_bf, mask);
    k_mfma_blk<<<1024, 256, 0, stream>>>(h_bf, WblkT, b_blk, z_bf, sumP, sumsqP);
    k_bnfin<<<128, 256, 0, stream>>>(sumP, sumsqP, gamma, beta, scale, shift);
    k_logits<<<512, 256, 0, stream>>>(h_bf, z_bf, scale, shift, W_fc, b_fc, mask, gumbel, t_buf);
    k_softmax<<<256, 256, 0, stream>>>(t_buf, w_buf);
    k_pool<<<dim3(16, 32), 256, 0, stream>>>(x, w_buf, pp);
    k_reduce_pool<<<256, 256, 0, stream>>>(pp, out);
}